// Round 12
// baseline (1730.296 us; speedup 1.0000x reference)
//
#include <hip/hip_runtime.h>

// ---------------------------------------------------------------------------
// SharedOnlyMLP r12: 2 independent blocks/CU for HW wave-level overlap.
//   Both GEMMs: 4-wave blocks (256 thr), tile 256x128, per-wave 128x64
//   (r7-identical work profile: 12 ds_reads + 32 MFMA per BK-step),
//   3-ring of 24KB LDS buffers (72KB/block -> 2 blocks/CU), stage dist 2,
//   vmcnt(6) counted waits, proven XOR swizzle both sides.
//   i8gu: BK=64 mfma_i32_16x16x64_i8, interleaved gate/up epilogue.
//   down: BK=32 mfma_f32_16x16x32_bf16, T=344.
//   Mechanism: two barrier groups per CU desync -> one block's LDS phase
//   overlaps the other's MFMA phase (m114 co-schedule).
// ---------------------------------------------------------------------------

typedef __attribute__((ext_vector_type(8))) __bf16 bf16x8;
typedef __attribute__((ext_vector_type(4))) float f32x4;
typedef __attribute__((ext_vector_type(8))) unsigned short ushort8;
typedef __attribute__((ext_vector_type(4))) int i32x4;

#define D_MODEL 4096
#define D_FF    11008
#define NTOK    8192

static __device__ __forceinline__ unsigned short f32_to_bf16(float f) {
    union { float f; unsigned u; } v; v.f = f;
    unsigned r = v.u + 0x7fffu + ((v.u >> 16) & 1u);
    return (unsigned short)(r >> 16);
}
static __device__ __forceinline__ void gload_lds16(const void* g, void* l) {
    __builtin_amdgcn_global_load_lds(
        (const __attribute__((address_space(1))) void*)g,
        (__attribute__((address_space(3))) void*)l, 16, 0, 0);
}

// ---- pack gate+up int32 -> interleaved int8 (16-row groups) ----
__global__ __launch_bounds__(256)
void pack_gu_kernel(const int* __restrict__ gw, const int* __restrict__ uw,
                    signed char* __restrict__ out)
{
    long long i = ((long long)blockIdx.x * 256 + threadIdx.x) * 8;
    const int r = (int)(i >> 12);
    const int k = (int)(i & 4095);
    const int src_row = ((r >> 5) << 4) + (r & 15);
    const int* src = ((r >> 4) & 1) ? uw : gw;
    const int* p = src + (size_t)src_row * D_MODEL + k;
    int4 w0 = *(const int4*)(p);
    int4 w1 = *(const int4*)(p + 4);
    union { signed char c[8]; unsigned long long u; } rr;
    rr.c[0] = (signed char)w0.x; rr.c[1] = (signed char)w0.y;
    rr.c[2] = (signed char)w0.z; rr.c[3] = (signed char)w0.w;
    rr.c[4] = (signed char)w1.x; rr.c[5] = (signed char)w1.y;
    rr.c[6] = (signed char)w1.z; rr.c[7] = (signed char)w1.w;
    *(unsigned long long*)(out + i) = rr.u;
}

// ---- weight dequant (down-proj): int32 * s[row] -> bf16 ----
__global__ __launch_bounds__(256)
void dequant_w_kernel(const int* __restrict__ w, const float* __restrict__ s,
                      unsigned short* __restrict__ out, int cols, long long total)
{
    long long i = ((long long)blockIdx.x * 256 + threadIdx.x) * 8;
    if (i >= total) return;
    float sc = s[(int)(i / cols)];
    int4 w0 = *(const int4*)(w + i);
    int4 w1 = *(const int4*)(w + i + 4);
    ushort8 r;
    r[0] = f32_to_bf16((float)w0.x * sc);
    r[1] = f32_to_bf16((float)w0.y * sc);
    r[2] = f32_to_bf16((float)w0.z * sc);
    r[3] = f32_to_bf16((float)w0.w * sc);
    r[4] = f32_to_bf16((float)w1.x * sc);
    r[5] = f32_to_bf16((float)w1.y * sc);
    r[6] = f32_to_bf16((float)w1.z * sc);
    r[7] = f32_to_bf16((float)w1.w * sc);
    *(ushort8*)(out + i) = r;
}

// ---- x: f32 -> per-row int8 + scale ----
__global__ __launch_bounds__(256)
void quant_x_kernel(const float* __restrict__ x, signed char* __restrict__ xq,
                    float* __restrict__ xs)
{
    __shared__ float red[4];
    const int row = blockIdx.x;
    const int t   = threadIdx.x;
    const float* xr = x + (size_t)row * D_MODEL;
    float4 v0 = *(const float4*)(xr + t * 16);
    float4 v1 = *(const float4*)(xr + t * 16 + 4);
    float4 v2 = *(const float4*)(xr + t * 16 + 8);
    float4 v3 = *(const float4*)(xr + t * 16 + 12);
    float m = fabsf(v0.x);
    m = fmaxf(m, fabsf(v0.y)); m = fmaxf(m, fabsf(v0.z)); m = fmaxf(m, fabsf(v0.w));
    m = fmaxf(m, fabsf(v1.x)); m = fmaxf(m, fabsf(v1.y)); m = fmaxf(m, fabsf(v1.z)); m = fmaxf(m, fabsf(v1.w));
    m = fmaxf(m, fabsf(v2.x)); m = fmaxf(m, fabsf(v2.y)); m = fmaxf(m, fabsf(v2.z)); m = fmaxf(m, fabsf(v2.w));
    m = fmaxf(m, fabsf(v3.x)); m = fmaxf(m, fabsf(v3.y)); m = fmaxf(m, fabsf(v3.z)); m = fmaxf(m, fabsf(v3.w));
    #pragma unroll
    for (int o = 32; o > 0; o >>= 1) m = fmaxf(m, __shfl_xor(m, o));
    if ((t & 63) == 0) red[t >> 6] = m;
    __syncthreads();
    m = fmaxf(fmaxf(red[0], red[1]), fmaxf(red[2], red[3]));
    m = fmaxf(m, 1e-20f);
    const float inv = 127.0f / m;
    if (t == 0) xs[row] = m / 127.0f;
    union { signed char c[16]; int4 i; } r;
    #pragma unroll
    for (int j = 0; j < 4; ++j) {
        float4 v = (j == 0) ? v0 : (j == 1) ? v1 : (j == 2) ? v2 : v3;
        r.c[j*4+0] = (signed char)(int)rintf(fminf(fmaxf(v.x*inv,-127.f),127.f));
        r.c[j*4+1] = (signed char)(int)rintf(fminf(fmaxf(v.y*inv,-127.f),127.f));
        r.c[j*4+2] = (signed char)(int)rintf(fminf(fmaxf(v.z*inv,-127.f),127.f));
        r.c[j*4+3] = (signed char)(int)rintf(fminf(fmaxf(v.w*inv,-127.f),127.f));
    }
    *(int4*)(xq + (size_t)row * D_MODEL + t * 16) = r.i;
}

// ---------------------------------------------------------------------------
// Fused gate+up i8 GEMM. 4 waves, tile 256x128(il). BK=64 steps.
// LDS buffer 24KB: A [256 rows][64B] at +0, B [128 rows][64B] at +16384.
// 3-ring (72KB); stage s+2 during s (6 gloads); vmcnt(6)/step; 1 barrier/step.
// ---------------------------------------------------------------------------
__global__ __launch_bounds__(256, 2)
void gemm_i8gu(const signed char* __restrict__ A,
               const signed char* __restrict__ B,   // interleaved [2*D_FF][K]
               unsigned short* __restrict__ H,
               const float* __restrict__ xs,
               const float* __restrict__ gs,
               const float* __restrict__ us,
               int M, int NH, int K)
{
    extern __shared__ char smem[];
    const int tid = threadIdx.x;
    const int l   = tid & 63;
    const int w   = tid >> 6;        // 0..3
    const int wm  = w >> 1;          // 0..1
    const int wn  = w & 1;           // 0..1

    const int nbx  = gridDim.x;
    const int nwg  = nbx * gridDim.y;
    const int orig = blockIdx.y * nbx + blockIdx.x;
    const int cpx  = nwg >> 3;
    const int swz  = (orig & 7) * cpx + (orig >> 3);
    const int bn = swz % nbx, bm = swz / nbx;
    const int m0 = bm * 256, n0 = bn * 128;   // n0 over interleaved rows

    // staging: 64-row groups; thread -> row w*16 + l/4, 16B chunk (l&3), preswz
    const int sr0 = w * 16 + (l >> 2);
    const int sc  = ((l & 3) ^ ((sr0 >> 1) & 3)) << 4;    // bytes
    const signed char* gA = A + (size_t)(m0 + sr0) * K + sc;
    const signed char* gB = B + (size_t)(n0 + sr0) * K + sc;
    const size_t ld64 = (size_t)64 * K;

    const int s4v = l >> 4;
    const int rA = wm * 128 + (l & 15);
    const int rB = wn * 64  + (l & 15);
    const int offA = rA * 64 + ((s4v << 4) ^ (((rA >> 1) & 3) << 4));
    const int offB = 16384 + rB * 64 + ((s4v << 4) ^ (((rB >> 1) & 3) << 4));

    i32x4 acc[8][4] = {};
    i32x4 af[8], bfr[4];

    const int BUF = 24576;

#define SBAR()  __builtin_amdgcn_sched_barrier(0)
#define BAR()   __builtin_amdgcn_s_barrier()
#define VM6()   asm volatile("s_waitcnt vmcnt(6)" ::: "memory")

#define ST_A(SS, NXT) do { \
    const signed char* p_ = gA + ((size_t)(SS) << 6); \
    gload_lds16(p_,            smem + (NXT) +         (w << 10)); \
    gload_lds16(p_ + ld64,     smem + (NXT) + 4096  + (w << 10)); \
    gload_lds16(p_ + 2 * ld64, smem + (NXT) + 8192  + (w << 10)); \
    gload_lds16(p_ + 3 * ld64, smem + (NXT) + 12288 + (w << 10)); } while (0)
#define ST_B(SS, NXT) do { \
    const signed char* p_ = gB + ((size_t)(SS) << 6); \
    gload_lds16(p_,        smem + (NXT) + 16384 + (w << 10)); \
    gload_lds16(p_ + ld64, smem + (NXT) + 20480 + (w << 10)); } while (0)

#define STEP8(CUR, NXT, SS) do { \
    ST_A(SS, NXT); \
    ST_B(SS, NXT); \
    af[0] = *(const i32x4*)(smem + (CUR) + offA); \
    af[1] = *(const i32x4*)(smem + (CUR) + offA + 1024); \
    af[2] = *(const i32x4*)(smem + (CUR) + offA + 2048); \
    af[3] = *(const i32x4*)(smem + (CUR) + offA + 3072); \
    af[4] = *(const i32x4*)(smem + (CUR) + offA + 4096); \
    af[5] = *(const i32x4*)(smem + (CUR) + offA + 5120); \
    af[6] = *(const i32x4*)(smem + (CUR) + offA + 6144); \
    af[7] = *(const i32x4*)(smem + (CUR) + offA + 7168); \
    bfr[0] = *(const i32x4*)(smem + (CUR) + offB); \
    bfr[1] = *(const i32x4*)(smem + (CUR) + offB + 1024); \
    bfr[2] = *(const i32x4*)(smem + (CUR) + offB + 2048); \
    bfr[3] = *(const i32x4*)(smem + (CUR) + offB + 3072); \
    __builtin_amdgcn_s_setprio(1); \
    _Pragma("unroll") \
    for (int mi_ = 0; mi_ < 8; ++mi_) { \
        _Pragma("unroll") \
        for (int ni_ = 0; ni_ < 4; ++ni_) { \
            acc[mi_][ni_] = __builtin_amdgcn_mfma_i32_16x16x64_i8( \
                af[mi_], bfr[ni_], acc[mi_][ni_], 0, 0, 0); \
        } } \
    __builtin_amdgcn_s_setprio(0); \
    VM6(); SBAR(); BAR(); \
} while (0)

    // prologue: stage steps 0,1 into bufs 0,1 (12 loads); wait step 0's 6
    ST_A(0, 0);    ST_B(0, 0);
    ST_A(1, BUF);  ST_B(1, BUF);
    VM6(); SBAR(); BAR();

    const int T = K >> 6;            // 64
    int cur = 0, nxt = 2 * BUF;
    #pragma unroll 1
    for (int s = 0; s < T; ++s) {
        int ss = s + 2; if (ss >= T) ss -= T;   // wrapped restage (harmless)
        STEP8(cur, nxt, ss);
        cur += BUF; if (cur == 3 * BUF) cur = 0;
        nxt += BUF; if (nxt == 3 * BUF) nxt = 0;
    }
    asm volatile("s_waitcnt vmcnt(0)" ::: "memory");

    // epilogue: ni even = gate, ni odd = up (16-row interleave)
    const int er = (l >> 4) * 4;
    const int ec = l & 15;
    const int hbase = (n0 >> 1) + wn * 32;
    #pragma unroll
    for (int mi = 0; mi < 8; ++mi) {
        const int rowb = m0 + wm * 128 + mi * 16 + er;
        const float4 xsv = *(const float4*)(xs + rowb);
        #pragma unroll
        for (int p = 0; p < 2; ++p) {
            const int c = hbase + p * 16 + ec;
            const float sg = gs[c];
            const float su = us[c];
            #pragma unroll
            for (int q = 0; q < 4; ++q) {
                const float xsc = (q == 0) ? xsv.x : (q == 1) ? xsv.y
                                 : (q == 2) ? xsv.z : xsv.w;
                float g = (float)acc[mi][2*p][q]     * sg * xsc;
                float u = (float)acc[mi][2*p + 1][q] * su * xsc;
                float sig = 1.0f / (1.0f + __expf(-g));
                H[(size_t)(rowb + q) * NH + c] = f32_to_bf16(g * sig * u);
            }
        }
    }
#undef STEP8
#undef ST_A
#undef ST_B
#undef VM6
#undef BAR
#undef SBAR
}

// ---------------------------------------------------------------------------
// Down-proj bf16 GEMM. 4 waves, tile 256x128. BK=32 steps, 3-ring of 24KB.
// Same geometry as i8gu (A [256][64B], B [128][64B] per buffer). T=344.
// ---------------------------------------------------------------------------
__global__ __launch_bounds__(256, 2)
void gemm256_down(const unsigned short* __restrict__ A,
                  const unsigned short* __restrict__ B,
                  float* __restrict__ C,
                  int M, int N, int K)
{
    extern __shared__ char smem[];
    const int tid = threadIdx.x;
    const int l   = tid & 63;
    const int w   = tid >> 6;
    const int wm  = w >> 1;
    const int wn  = w & 1;

    const int nbx  = gridDim.x;
    const int nwg  = nbx * gridDim.y;
    const int orig = blockIdx.y * nbx + blockIdx.x;
    const int cpx  = nwg >> 3;
    const int swz  = (orig & 7) * cpx + (orig >> 3);
    const int bn = swz % nbx, bm = swz / nbx;
    const int m0 = bm * 256, n0 = bn * 128;

    const int sr0 = w * 16 + (l >> 2);
    const int sc  = ((l & 3) ^ ((sr0 >> 1) & 3)) << 3;    // elems (bf16)
    const unsigned short* gA = A + (size_t)(m0 + sr0) * K + sc;
    const unsigned short* gB = B + (size_t)(n0 + sr0) * K + sc;
    const size_t ld64 = (size_t)64 * K;

    const int s4v = l >> 4;
    const int rA = wm * 128 + (l & 15);
    const int rB = wn * 64  + (l & 15);
    const int offA = rA * 64 + ((s4v << 4) ^ (((rA >> 1) & 3) << 4));
    const int offB = 16384 + rB * 64 + ((s4v << 4) ^ (((rB >> 1) & 3) << 4));

    f32x4 acc[8][4] = {};
    bf16x8 af[8], bfr[4];

    const int BUF = 24576;

#define SBAR()  __builtin_amdgcn_sched_barrier(0)
#define BAR()   __builtin_amdgcn_s_barrier()
#define VM6()   asm volatile("s_waitcnt vmcnt(6)" ::: "memory")

#define ST_A2(SS, NXT) do { \
    const unsigned short* p_ = gA + ((size_t)(SS) << 5); \
    gload_lds16(p_,            smem + (NXT) +         (w << 10)); \
    gload_lds16(p_ + ld64,     smem + (NXT) + 4096  + (w << 10)); \
    gload_lds16(p_ + 2 * ld64, smem + (NXT) + 8192  + (w << 10)); \
    gload_lds16(p_ + 3 * ld64, smem + (NXT) + 12288 + (w << 10)); } while (0)
#define ST_B2(SS, NXT) do { \
    const unsigned short* p_ = gB + ((size_t)(SS) << 5); \
    gload_lds16(p_,        smem + (NXT) + 16384 + (w << 10)); \
    gload_lds16(p_ + ld64, smem + (NXT) + 20480 + (w << 10)); } while (0)

#define STEPD(CUR, NXT, SS) do { \
    ST_A2(SS, NXT); \
    ST_B2(SS, NXT); \
    af[0] = *(const bf16x8*)(smem + (CUR) + offA); \
    af[1] = *(const bf16x8*)(smem + (CUR) + offA + 1024); \
    af[2] = *(const bf16x8*)(smem + (CUR) + offA + 2048); \
    af[3] = *(const bf16x8*)(smem + (CUR) + offA + 3072); \
    af[4] = *(const bf16x8*)(smem + (CUR) + offA + 4096); \
    af[5] = *(const bf16x8*)(smem + (CUR) + offA + 5120); \
    af[6] = *(const bf16x8*)(smem + (CUR) + offA + 6144); \
    af[7] = *(const bf16x8*)(smem + (CUR) + offA + 7168); \
    bfr[0] = *(const bf16x8*)(smem + (CUR) + offB); \
    bfr[1] = *(const bf16x8*)(smem + (CUR) + offB + 1024); \
    bfr[2] = *(const bf16x8*)(smem + (CUR) + offB + 2048); \
    bfr[3] = *(const bf16x8*)(smem + (CUR) + offB + 3072); \
    __builtin_amdgcn_s_setprio(1); \
    _Pragma("unroll") \
    for (int mi_ = 0; mi_ < 8; ++mi_) { \
        _Pragma("unroll") \
        for (int ni_ = 0; ni_ < 4; ++ni_) { \
            acc[mi_][ni_] = __builtin_amdgcn_mfma_f32_16x16x32_bf16( \
                af[mi_], bfr[ni_], acc[mi_][ni_], 0, 0, 0); \
        } } \
    __builtin_amdgcn_s_setprio(0); \
    VM6(); SBAR(); BAR(); \
} while (0)

    ST_A2(0, 0);    ST_B2(0, 0);
    ST_A2(1, BUF);  ST_B2(1, BUF);
    VM6(); SBAR(); BAR();

    const int T = K >> 5;            // 344
    int cur = 0, nxt = 2 * BUF;
    #pragma unroll 1
    for (int s = 0; s < T; ++s) {
        int ss = s + 2; if (ss >= T) ss -= T;
        STEPD(cur, nxt, ss);
        cur += BUF; if (cur == 3 * BUF) cur = 0;
        nxt += BUF; if (nxt == 3 * BUF) nxt = 0;
    }
    asm volatile("s_waitcnt vmcnt(0)" ::: "memory");

    const int er = (l >> 4) * 4;
    const int ec = l & 15;
    #pragma unroll
    for (int mi = 0; mi < 8; ++mi) {
        #pragma unroll
        for (int ni = 0; ni < 4; ++ni) {
            #pragma unroll
            for (int q = 0; q < 4; ++q) {
                int row = m0 + wm * 128 + mi * 16 + er + q;
                int col = n0 + wn * 64  + ni * 16 + ec;
                C[(size_t)row * N + col] = acc[mi][ni][q];
            }
        }
    }
#undef STEPD
#undef ST_A2
#undef ST_B2
#undef VM6
#undef BAR
#undef SBAR
}

extern "C" void kernel_launch(void* const* d_in, const int* in_sizes, int n_in,
                              void* d_out, int out_size, void* d_ws, size_t ws_size,
                              hipStream_t stream)
{
    const float* x  = (const float*)d_in[0];
    const int*   gw = (const int*)  d_in[1];
    const float* gs = (const float*)d_in[2];
    const int*   uw = (const int*)  d_in[3];
    const float* us = (const float*)d_in[4];
    const int*   dw = (const int*)  d_in[5];
    const float* dsc= (const float*)d_in[6];

    char* ws = (char*)d_ws;
    signed char*    Xq   = (signed char*)ws;    ws += (size_t)NTOK * D_MODEL;
    float*          xs   = (float*)ws;          ws += (size_t)NTOK * 4;
    signed char*    Wgu8 = (signed char*)ws;    ws += (size_t)2 * D_FF * D_MODEL;
    unsigned short* Wd   = (unsigned short*)ws; ws += (size_t)D_MODEL * D_FF * 2;
    unsigned short* H    = (unsigned short*)ws;

    const long long wtot  = (long long)D_FF * D_MODEL;
    const long long gutot = 2LL * wtot;

    hipFuncSetAttribute(reinterpret_cast<const void*>(gemm_i8gu),
                        hipFuncAttributeMaxDynamicSharedMemorySize, 73728);
    hipFuncSetAttribute(reinterpret_cast<const void*>(gemm256_down),
                        hipFuncAttributeMaxDynamicSharedMemorySize, 73728);

    pack_gu_kernel  <<<(int)(gutot / 2048), 256, 0, stream>>>(gw, uw, Wgu8);
    dequant_w_kernel<<<(int)(wtot  / 2048), 256, 0, stream>>>(dw, dsc, Wd, D_FF, wtot);
    quant_x_kernel  <<<NTOK, 256, 0, stream>>>(x, Xq, xs);

    // fused gate+up: H = silu(Xq@Wg^T * gs*xs) * (Xq@Wu^T * us*xs)
    dim3 g1(2 * D_FF / 128, NTOK / 256);   // 172 x 32 = 5504 blocks (%8==0)
    gemm_i8gu<<<g1, 256, 73728, stream>>>(Xq, Wgu8, H, xs, gs, us,
                                          NTOK, D_FF, D_MODEL);

    // out = H @ Wd^T -> f32
    dim3 g3(D_MODEL / 128, NTOK / 256);    // 32 x 32 = 1024 blocks (%8==0)
    gemm256_down<<<g3, 256, 73728, stream>>>(H, Wd, (float*)d_out,
                                             NTOK, D_MODEL, D_FF);
}

// Round 13
// 1632.884 us; speedup vs baseline: 1.0597x; 1.0597x over previous
//
#include <hip/hip_runtime.h>

// ---------------------------------------------------------------------------
// SharedOnlyMLP r13: 128x128 per-wave tiles, 1 wave/SIMD, intra-wave overlap.
//   Both GEMMs: 4-wave blocks (256 thr, launch_bounds(256,1)), 256x256 tile,
//   per-wave 128x128 (16 ds_reads -> 64 MFMA per BK-step: LDS/MFMA ratio
//   -33% vs r7). acc[8][8] (256 regs) + double-buffered frag sets (128) fit
//   the 512-reg budget at 1 wave/SIMD. 4-ring x 32KB LDS (128KB), stage
//   dist 3 (8 gloads/wave/step), vmcnt(8)+barrier once per step. Prefetch
//   reads for step s+1 issue before step-s MFMAs (sched_barrier pinned) and
//   complete under them (in-order lgkm counted wait).
//   i8gu: BK=64 mfma_i32_16x16x64_i8, interleaved gate/up epilogue.
//   down: BK=32 mfma_f32_16x16x32_bf16, T=344.
// ---------------------------------------------------------------------------

typedef __attribute__((ext_vector_type(8))) __bf16 bf16x8;
typedef __attribute__((ext_vector_type(4))) float f32x4;
typedef __attribute__((ext_vector_type(8))) unsigned short ushort8;
typedef __attribute__((ext_vector_type(4))) int i32x4;

#define D_MODEL 4096
#define D_FF    11008
#define NTOK    8192

static __device__ __forceinline__ unsigned short f32_to_bf16(float f) {
    union { float f; unsigned u; } v; v.f = f;
    unsigned r = v.u + 0x7fffu + ((v.u >> 16) & 1u);
    return (unsigned short)(r >> 16);
}
static __device__ __forceinline__ void gload_lds16(const void* g, void* l) {
    __builtin_amdgcn_global_load_lds(
        (const __attribute__((address_space(1))) void*)g,
        (__attribute__((address_space(3))) void*)l, 16, 0, 0);
}

// ---- pack gate+up int32 -> interleaved int8 (16-row groups) ----
__global__ __launch_bounds__(256)
void pack_gu_kernel(const int* __restrict__ gw, const int* __restrict__ uw,
                    signed char* __restrict__ out)
{
    long long i = ((long long)blockIdx.x * 256 + threadIdx.x) * 8;
    const int r = (int)(i >> 12);
    const int k = (int)(i & 4095);
    const int src_row = ((r >> 5) << 4) + (r & 15);
    const int* src = ((r >> 4) & 1) ? uw : gw;
    const int* p = src + (size_t)src_row * D_MODEL + k;
    int4 w0 = *(const int4*)(p);
    int4 w1 = *(const int4*)(p + 4);
    union { signed char c[8]; unsigned long long u; } rr;
    rr.c[0] = (signed char)w0.x; rr.c[1] = (signed char)w0.y;
    rr.c[2] = (signed char)w0.z; rr.c[3] = (signed char)w0.w;
    rr.c[4] = (signed char)w1.x; rr.c[5] = (signed char)w1.y;
    rr.c[6] = (signed char)w1.z; rr.c[7] = (signed char)w1.w;
    *(unsigned long long*)(out + i) = rr.u;
}

// ---- weight dequant (down-proj): int32 * s[row] -> bf16 ----
__global__ __launch_bounds__(256)
void dequant_w_kernel(const int* __restrict__ w, const float* __restrict__ s,
                      unsigned short* __restrict__ out, int cols, long long total)
{
    long long i = ((long long)blockIdx.x * 256 + threadIdx.x) * 8;
    if (i >= total) return;
    float sc = s[(int)(i / cols)];
    int4 w0 = *(const int4*)(w + i);
    int4 w1 = *(const int4*)(w + i + 4);
    ushort8 r;
    r[0] = f32_to_bf16((float)w0.x * sc);
    r[1] = f32_to_bf16((float)w0.y * sc);
    r[2] = f32_to_bf16((float)w0.z * sc);
    r[3] = f32_to_bf16((float)w0.w * sc);
    r[4] = f32_to_bf16((float)w1.x * sc);
    r[5] = f32_to_bf16((float)w1.y * sc);
    r[6] = f32_to_bf16((float)w1.z * sc);
    r[7] = f32_to_bf16((float)w1.w * sc);
    *(ushort8*)(out + i) = r;
}

// ---- x: f32 -> per-row int8 + scale ----
__global__ __launch_bounds__(256)
void quant_x_kernel(const float* __restrict__ x, signed char* __restrict__ xq,
                    float* __restrict__ xs)
{
    __shared__ float red[4];
    const int row = blockIdx.x;
    const int t   = threadIdx.x;
    const float* xr = x + (size_t)row * D_MODEL;
    float4 v0 = *(const float4*)(xr + t * 16);
    float4 v1 = *(const float4*)(xr + t * 16 + 4);
    float4 v2 = *(const float4*)(xr + t * 16 + 8);
    float4 v3 = *(const float4*)(xr + t * 16 + 12);
    float m = fabsf(v0.x);
    m = fmaxf(m, fabsf(v0.y)); m = fmaxf(m, fabsf(v0.z)); m = fmaxf(m, fabsf(v0.w));
    m = fmaxf(m, fabsf(v1.x)); m = fmaxf(m, fabsf(v1.y)); m = fmaxf(m, fabsf(v1.z)); m = fmaxf(m, fabsf(v1.w));
    m = fmaxf(m, fabsf(v2.x)); m = fmaxf(m, fabsf(v2.y)); m = fmaxf(m, fabsf(v2.z)); m = fmaxf(m, fabsf(v2.w));
    m = fmaxf(m, fabsf(v3.x)); m = fmaxf(m, fabsf(v3.y)); m = fmaxf(m, fabsf(v3.z)); m = fmaxf(m, fabsf(v3.w));
    #pragma unroll
    for (int o = 32; o > 0; o >>= 1) m = fmaxf(m, __shfl_xor(m, o));
    if ((t & 63) == 0) red[t >> 6] = m;
    __syncthreads();
    m = fmaxf(fmaxf(red[0], red[1]), fmaxf(red[2], red[3]));
    m = fmaxf(m, 1e-20f);
    const float inv = 127.0f / m;
    if (t == 0) xs[row] = m / 127.0f;
    union { signed char c[16]; int4 i; } r;
    #pragma unroll
    for (int j = 0; j < 4; ++j) {
        float4 v = (j == 0) ? v0 : (j == 1) ? v1 : (j == 2) ? v2 : v3;
        r.c[j*4+0] = (signed char)(int)rintf(fminf(fmaxf(v.x*inv,-127.f),127.f));
        r.c[j*4+1] = (signed char)(int)rintf(fminf(fmaxf(v.y*inv,-127.f),127.f));
        r.c[j*4+2] = (signed char)(int)rintf(fminf(fmaxf(v.z*inv,-127.f),127.f));
        r.c[j*4+3] = (signed char)(int)rintf(fminf(fmaxf(v.w*inv,-127.f),127.f));
    }
    *(int4*)(xq + (size_t)row * D_MODEL + t * 16) = r.i;
}

// ---------------------------------------------------------------------------
// Fused gate+up i8 GEMM. 4 waves (2Mx2N), per-wave 128x128(il). BK=64.
// Ring slot (32KB): A [256][64B] at +0, B [256][64B] at +16384; 4 slots.
// Step s: stage(s+3) (8 gloads); prefetch frags(s+1) from slot (s+1)%4
// (16 ds_reads, alternate reg set); 64 MFMA on current set; vmcnt(8); bar.
// ---------------------------------------------------------------------------
__global__ __launch_bounds__(256, 1)
void gemm_i8gu(const signed char* __restrict__ A,
               const signed char* __restrict__ B,   // interleaved [2*D_FF][K]
               unsigned short* __restrict__ H,
               const float* __restrict__ xs,
               const float* __restrict__ gs,
               const float* __restrict__ us,
               int M, int NH, int K)
{
    extern __shared__ char smem[];
    const int tid = threadIdx.x;
    const int l   = tid & 63;
    const int w   = tid >> 6;        // 0..3
    const int wm  = w >> 1;          // 0..1
    const int wn  = w & 1;           // 0..1

    const int nbx  = gridDim.x;
    const int nwg  = nbx * gridDim.y;
    const int orig = blockIdx.y * nbx + blockIdx.x;
    const int cpx  = nwg >> 3;
    const int swz  = (orig & 7) * cpx + (orig >> 3);
    const int bn = swz % nbx, bm = swz / nbx;
    const int m0 = bm * 256, n0 = bn * 256;   // n0 over interleaved rows

    // staging: wave w owns rows [w*64, w*64+64) of both panels; 4 instrs each
    const int st_r = w * 64 + (l >> 2);
    const int st_c = ((l & 3) ^ ((st_r >> 1) & 3)) << 4;   // bytes, pre-swizzled
    const signed char* gA = A + (size_t)(m0 + st_r) * K + st_c;
    const signed char* gB = B + (size_t)(n0 + st_r) * K + st_c;
    const size_t ld16 = (size_t)16 * K;

    // frag offsets (r7-proven swizzle; constant across 16-row frag steps)
    const int s4v = l >> 4;
    const int rA = wm * 128 + (l & 15);
    const int rB = wn * 128 + (l & 15);
    const int offA = rA * 64 + ((s4v << 4) ^ (((rA >> 1) & 3) << 4));
    const int offB = 16384 + rB * 64 + ((s4v << 4) ^ (((rB >> 1) & 3) << 4));

    i32x4 acc[8][8] = {};
    i32x4 a0[8], b0[8], a1[8], b1[8];   // named double-buffered frag sets

#define SBAR()  __builtin_amdgcn_sched_barrier(0)
#define BAR()   __builtin_amdgcn_s_barrier()
#define VM8()   asm volatile("s_waitcnt vmcnt(8)" ::: "memory")

#define ST_AB(SS, SLOT) do { \
    const signed char* pa_ = gA + ((size_t)(SS) << 6); \
    const signed char* pb_ = gB + ((size_t)(SS) << 6); \
    gload_lds16(pa_,            smem + (SLOT) + (w << 12)); \
    gload_lds16(pa_ + ld16,     smem + (SLOT) + (w << 12) + 1024); \
    gload_lds16(pa_ + 2 * ld16, smem + (SLOT) + (w << 12) + 2048); \
    gload_lds16(pa_ + 3 * ld16, smem + (SLOT) + (w << 12) + 3072); \
    gload_lds16(pb_,            smem + (SLOT) + 16384 + (w << 12)); \
    gload_lds16(pb_ + ld16,     smem + (SLOT) + 16384 + (w << 12) + 1024); \
    gload_lds16(pb_ + 2 * ld16, smem + (SLOT) + 16384 + (w << 12) + 2048); \
    gload_lds16(pb_ + 3 * ld16, smem + (SLOT) + 16384 + (w << 12) + 3072); } while (0)

#define LD_FRAGS(FA, FB, SLOT) do { \
    _Pragma("unroll") \
    for (int f_ = 0; f_ < 8; ++f_) { \
        FA[f_] = *(const i32x4*)(smem + (SLOT) + offA + (f_ << 10)); \
        FB[f_] = *(const i32x4*)(smem + (SLOT) + offB + (f_ << 10)); \
    } } while (0)

#define MFMA64(FA, FB) do { \
    __builtin_amdgcn_s_setprio(1); \
    _Pragma("unroll") \
    for (int mi_ = 0; mi_ < 8; ++mi_) { \
        _Pragma("unroll") \
        for (int ni_ = 0; ni_ < 8; ++ni_) { \
            acc[mi_][ni_] = __builtin_amdgcn_mfma_i32_16x16x64_i8( \
                FA[mi_], FB[ni_], acc[mi_][ni_], 0, 0, 0); \
        } } \
    __builtin_amdgcn_s_setprio(0); } while (0)

// step s: PRE=(s+1)%4 slot, NXT=(s+3)%4 slot; CA/CB consumed, NA/NB prefetched
#define STEP(PRE, NXT, SS, CA, CB, NA, NB) do { \
    ST_AB(SS, NXT); \
    LD_FRAGS(NA, NB, PRE); \
    SBAR(); \
    MFMA64(CA, CB); \
    SBAR(); \
    VM8(); BAR(); \
} while (0)

    // prologue: stage steps 0,1,2 into slots 0,1,2 (24 gloads/wave);
    // vmcnt(8) -> stages 0,1 complete. Preload frags(0) from slot 0.
    ST_AB(0, 0);
    ST_AB(1, 32768);
    ST_AB(2, 65536);
    VM8(); SBAR(); BAR();
    LD_FRAGS(a0, b0, 0);

    const int T = K >> 6;            // 64; T%4==0
    #pragma unroll 1
    for (int s = 0; s < T; s += 4) {
        int s3 = s + 3; if (s3 >= T) s3 -= T;   // wrapped restage (harmless)
        int s4 = s + 4; if (s4 >= T) s4 -= T;
        int s5 = s + 5; if (s5 >= T) s5 -= T;
        int s6 = s + 6; if (s6 >= T) s6 -= T;
        STEP(32768, 98304, s3, a0, b0, a1, b1);
        STEP(65536, 0,     s4, a1, b1, a0, b0);
        STEP(98304, 32768, s5, a0, b0, a1, b1);
        STEP(0,     65536, s6, a1, b1, a0, b0);
    }
    asm volatile("s_waitcnt vmcnt(0)" ::: "memory");

    // epilogue: ni even = gate, ni odd = up (16-row interleave)
    const int er = (l >> 4) * 4;
    const int ec = l & 15;
    const int hbase = (n0 >> 1) + wn * 64;
    #pragma unroll
    for (int mi = 0; mi < 8; ++mi) {
        const int rowb = m0 + wm * 128 + mi * 16 + er;
        const float4 xsv = *(const float4*)(xs + rowb);
        #pragma unroll
        for (int p = 0; p < 4; ++p) {
            const int c = hbase + p * 16 + ec;
            const float sg = gs[c];
            const float su = us[c];
            #pragma unroll
            for (int q = 0; q < 4; ++q) {
                const float xsc = (q == 0) ? xsv.x : (q == 1) ? xsv.y
                                 : (q == 2) ? xsv.z : xsv.w;
                float g = (float)acc[mi][2*p][q]     * sg * xsc;
                float u = (float)acc[mi][2*p + 1][q] * su * xsc;
                float sig = 1.0f / (1.0f + __expf(-g));
                H[(size_t)(rowb + q) * NH + c] = f32_to_bf16(g * sig * u);
            }
        }
    }
#undef STEP
#undef MFMA64
#undef LD_FRAGS
#undef ST_AB
#undef VM8
#undef BAR
#undef SBAR
}

// ---------------------------------------------------------------------------
// Down-proj bf16 GEMM, same structure. BK=32 (rows are 32 bf16 = 64B), T=344.
// ---------------------------------------------------------------------------
__global__ __launch_bounds__(256, 1)
void gemm256_down(const unsigned short* __restrict__ A,
                  const unsigned short* __restrict__ B,
                  float* __restrict__ C,
                  int M, int N, int K)
{
    extern __shared__ char smem[];
    const int tid = threadIdx.x;
    const int l   = tid & 63;
    const int w   = tid >> 6;
    const int wm  = w >> 1;
    const int wn  = w & 1;

    const int nbx  = gridDim.x;
    const int nwg  = nbx * gridDim.y;
    const int orig = blockIdx.y * nbx + blockIdx.x;
    const int cpx  = nwg >> 3;
    const int swz  = (orig & 7) * cpx + (orig >> 3);
    const int bn = swz % nbx, bm = swz / nbx;
    const int m0 = bm * 256, n0 = bn * 256;

    const int st_r = w * 64 + (l >> 2);
    const int st_c = ((l & 3) ^ ((st_r >> 1) & 3)) << 3;   // elems (bf16)
    const unsigned short* gA = A + (size_t)(m0 + st_r) * K + st_c;
    const unsigned short* gB = B + (size_t)(n0 + st_r) * K + st_c;
    const size_t ld16 = (size_t)16 * K;

    const int s4v = l >> 4;
    const int rA = wm * 128 + (l & 15);
    const int rB = wn * 128 + (l & 15);
    const int offA = rA * 64 + ((s4v << 4) ^ (((rA >> 1) & 3) << 4));
    const int offB = 16384 + rB * 64 + ((s4v << 4) ^ (((rB >> 1) & 3) << 4));

    f32x4 acc[8][8] = {};
    bf16x8 a0[8], b0[8], a1[8], b1[8];

#define SBAR()  __builtin_amdgcn_sched_barrier(0)
#define BAR()   __builtin_amdgcn_s_barrier()
#define VM8()   asm volatile("s_waitcnt vmcnt(8)" ::: "memory")

#define ST_AB(SS, SLOT) do { \
    const unsigned short* pa_ = gA + ((size_t)(SS) << 5); \
    const unsigned short* pb_ = gB + ((size_t)(SS) << 5); \
    gload_lds16(pa_,            smem + (SLOT) + (w << 12)); \
    gload_lds16(pa_ + ld16,     smem + (SLOT) + (w << 12) + 1024); \
    gload_lds16(pa_ + 2 * ld16, smem + (SLOT) + (w << 12) + 2048); \
    gload_lds16(pa_ + 3 * ld16, smem + (SLOT) + (w << 12) + 3072); \
    gload_lds16(pb_,            smem + (SLOT) + 16384 + (w << 12)); \
    gload_lds16(pb_ + ld16,     smem + (SLOT) + 16384 + (w << 12) + 1024); \
    gload_lds16(pb_ + 2 * ld16, smem + (SLOT) + 16384 + (w << 12) + 2048); \
    gload_lds16(pb_ + 3 * ld16, smem + (SLOT) + 16384 + (w << 12) + 3072); } while (0)

#define LD_FRAGS(FA, FB, SLOT) do { \
    _Pragma("unroll") \
    for (int f_ = 0; f_ < 8; ++f_) { \
        FA[f_] = *(const bf16x8*)(smem + (SLOT) + offA + (f_ << 10)); \
        FB[f_] = *(const bf16x8*)(smem + (SLOT) + offB + (f_ << 10)); \
    } } while (0)

#define MFMA64(FA, FB) do { \
    __builtin_amdgcn_s_setprio(1); \
    _Pragma("unroll") \
    for (int mi_ = 0; mi_ < 8; ++mi_) { \
        _Pragma("unroll") \
        for (int ni_ = 0; ni_ < 8; ++ni_) { \
            acc[mi_][ni_] = __builtin_amdgcn_mfma_f32_16x16x32_bf16( \
                FA[mi_], FB[ni_], acc[mi_][ni_], 0, 0, 0); \
        } } \
    __builtin_amdgcn_s_setprio(0); } while (0)

#define STEP(PRE, NXT, SS, CA, CB, NA, NB) do { \
    ST_AB(SS, NXT); \
    LD_FRAGS(NA, NB, PRE); \
    SBAR(); \
    MFMA64(CA, CB); \
    SBAR(); \
    VM8(); BAR(); \
} while (0)

    ST_AB(0, 0);
    ST_AB(1, 32768);
    ST_AB(2, 65536);
    VM8(); SBAR(); BAR();
    LD_FRAGS(a0, b0, 0);

    const int T = K >> 5;            // 344; T%4==0
    #pragma unroll 1
    for (int s = 0; s < T; s += 4) {
        int s3 = s + 3; if (s3 >= T) s3 -= T;
        int s4 = s + 4; if (s4 >= T) s4 -= T;
        int s5 = s + 5; if (s5 >= T) s5 -= T;
        int s6 = s + 6; if (s6 >= T) s6 -= T;
        STEP(32768, 98304, s3, a0, b0, a1, b1);
        STEP(65536, 0,     s4, a1, b1, a0, b0);
        STEP(98304, 32768, s5, a0, b0, a1, b1);
        STEP(0,     65536, s6, a1, b1, a0, b0);
    }
    asm volatile("s_waitcnt vmcnt(0)" ::: "memory");

    const int er = (l >> 4) * 4;
    const int ec = l & 15;
    #pragma unroll
    for (int mi = 0; mi < 8; ++mi) {
        #pragma unroll
        for (int ni = 0; ni < 8; ++ni) {
            #pragma unroll
            for (int q = 0; q < 4; ++q) {
                int row = m0 + wm * 128 + mi * 16 + er + q;
                int col = n0 + wn * 128 + ni * 16 + ec;
                C[(size_t)row * N + col] = acc[mi][ni][q];
            }
        }
    }
#undef STEP
#undef MFMA64
#undef LD_FRAGS
#undef ST_AB
#undef VM8
#undef BAR
#undef SBAR
}

extern "C" void kernel_launch(void* const* d_in, const int* in_sizes, int n_in,
                              void* d_out, int out_size, void* d_ws, size_t ws_size,
                              hipStream_t stream)
{
    const float* x  = (const float*)d_in[0];
    const int*   gw = (const int*)  d_in[1];
    const float* gs = (const float*)d_in[2];
    const int*   uw = (const int*)  d_in[3];
    const float* us = (const float*)d_in[4];
    const int*   dw = (const int*)  d_in[5];
    const float* dsc= (const float*)d_in[6];

    char* ws = (char*)d_ws;
    signed char*    Xq   = (signed char*)ws;    ws += (size_t)NTOK * D_MODEL;
    float*          xs   = (float*)ws;          ws += (size_t)NTOK * 4;
    signed char*    Wgu8 = (signed char*)ws;    ws += (size_t)2 * D_FF * D_MODEL;
    unsigned short* Wd   = (unsigned short*)ws; ws += (size_t)D_MODEL * D_FF * 2;
    unsigned short* H    = (unsigned short*)ws;

    const long long wtot  = (long long)D_FF * D_MODEL;
    const long long gutot = 2LL * wtot;

    hipFuncSetAttribute(reinterpret_cast<const void*>(gemm_i8gu),
                        hipFuncAttributeMaxDynamicSharedMemorySize, 131072);
    hipFuncSetAttribute(reinterpret_cast<const void*>(gemm256_down),
                        hipFuncAttributeMaxDynamicSharedMemorySize, 131072);

    pack_gu_kernel  <<<(int)(gutot / 2048), 256, 0, stream>>>(gw, uw, Wgu8);
    dequant_w_kernel<<<(int)(wtot  / 2048), 256, 0, stream>>>(dw, dsc, Wd, D_FF, wtot);
    quant_x_kernel  <<<NTOK, 256, 0, stream>>>(x, Xq, xs);

    // fused gate+up: H = silu(Xq@Wg^T * gs*xs) * (Xq@Wu^T * us*xs)
    dim3 g1(2 * D_FF / 256, NTOK / 256);   // 86 x 32 = 2752 blocks (%8==0)
    gemm_i8gu<<<g1, 256, 131072, stream>>>(Xq, Wgu8, H, xs, gs, us,
                                           NTOK, D_FF, D_MODEL);

    // out = H @ Wd^T -> f32
    dim3 g3(D_MODEL / 256, NTOK / 256);    // 16 x 32 = 512 blocks (%8==0)
    gemm256_down<<<g3, 256, 131072, stream>>>(H, Wd, (float*)d_out,
                                              NTOK, D_MODEL, D_FF);
}

// Round 14
// 1569.432 us; speedup vs baseline: 1.1025x; 1.0404x over previous
//
#include <hip/hip_runtime.h>

// ---------------------------------------------------------------------------
// SharedOnlyMLP r14 (convergence): best measured kernel per stage.
//   i8gu = r7 form: BK=64, 4-ring 32KB slots, 2 phases/step w/ barrier pairs,
//          vmcnt(4)/step, interleaved gate/up, in-register silu epilogue.
//   down = r10 form: bf16 BK=32, 4-ring 32KB slots, ONE barrier region/step
//          (12 ds_reads + 32 MFMA), vmcnt(4)/step. T=344.
//   Prepass: pack_gu (int8 interleave), dequant_w (Wd bf16), quant_x (int8).
//   Invariant found this session: step ~= LDS-time + MFMA-time; all source-
//   level desync levers (deep ring / merged barriers / reg prefetch /
//   2 blocks/CU / fat waves) are neutral or regress. ~50% MfmaUtil is this
//   structure's practical ceiling in plain HIP.
// ---------------------------------------------------------------------------

typedef __attribute__((ext_vector_type(8))) __bf16 bf16x8;
typedef __attribute__((ext_vector_type(4))) float f32x4;
typedef __attribute__((ext_vector_type(8))) unsigned short ushort8;
typedef __attribute__((ext_vector_type(4))) int i32x4;

#define D_MODEL 4096
#define D_FF    11008
#define NTOK    8192

static __device__ __forceinline__ unsigned short f32_to_bf16(float f) {
    union { float f; unsigned u; } v; v.f = f;
    unsigned r = v.u + 0x7fffu + ((v.u >> 16) & 1u);
    return (unsigned short)(r >> 16);
}
static __device__ __forceinline__ void gload_lds16(const void* g, void* l) {
    __builtin_amdgcn_global_load_lds(
        (const __attribute__((address_space(1))) void*)g,
        (__attribute__((address_space(3))) void*)l, 16, 0, 0);
}

// ---- pack gate+up int32 -> interleaved int8 (16-row groups) ----
__global__ __launch_bounds__(256)
void pack_gu_kernel(const int* __restrict__ gw, const int* __restrict__ uw,
                    signed char* __restrict__ out)
{
    long long i = ((long long)blockIdx.x * 256 + threadIdx.x) * 8;
    const int r = (int)(i >> 12);
    const int k = (int)(i & 4095);
    const int src_row = ((r >> 5) << 4) + (r & 15);
    const int* src = ((r >> 4) & 1) ? uw : gw;
    const int* p = src + (size_t)src_row * D_MODEL + k;
    int4 w0 = *(const int4*)(p);
    int4 w1 = *(const int4*)(p + 4);
    union { signed char c[8]; unsigned long long u; } rr;
    rr.c[0] = (signed char)w0.x; rr.c[1] = (signed char)w0.y;
    rr.c[2] = (signed char)w0.z; rr.c[3] = (signed char)w0.w;
    rr.c[4] = (signed char)w1.x; rr.c[5] = (signed char)w1.y;
    rr.c[6] = (signed char)w1.z; rr.c[7] = (signed char)w1.w;
    *(unsigned long long*)(out + i) = rr.u;
}

// ---- weight dequant (down-proj): int32 * s[row] -> bf16 ----
__global__ __launch_bounds__(256)
void dequant_w_kernel(const int* __restrict__ w, const float* __restrict__ s,
                      unsigned short* __restrict__ out, int cols, long long total)
{
    long long i = ((long long)blockIdx.x * 256 + threadIdx.x) * 8;
    if (i >= total) return;
    float sc = s[(int)(i / cols)];
    int4 w0 = *(const int4*)(w + i);
    int4 w1 = *(const int4*)(w + i + 4);
    ushort8 r;
    r[0] = f32_to_bf16((float)w0.x * sc);
    r[1] = f32_to_bf16((float)w0.y * sc);
    r[2] = f32_to_bf16((float)w0.z * sc);
    r[3] = f32_to_bf16((float)w0.w * sc);
    r[4] = f32_to_bf16((float)w1.x * sc);
    r[5] = f32_to_bf16((float)w1.y * sc);
    r[6] = f32_to_bf16((float)w1.z * sc);
    r[7] = f32_to_bf16((float)w1.w * sc);
    *(ushort8*)(out + i) = r;
}

// ---- x: f32 -> per-row int8 + scale ----
__global__ __launch_bounds__(256)
void quant_x_kernel(const float* __restrict__ x, signed char* __restrict__ xq,
                    float* __restrict__ xs)
{
    __shared__ float red[4];
    const int row = blockIdx.x;
    const int t   = threadIdx.x;
    const float* xr = x + (size_t)row * D_MODEL;
    float4 v0 = *(const float4*)(xr + t * 16);
    float4 v1 = *(const float4*)(xr + t * 16 + 4);
    float4 v2 = *(const float4*)(xr + t * 16 + 8);
    float4 v3 = *(const float4*)(xr + t * 16 + 12);
    float m = fabsf(v0.x);
    m = fmaxf(m, fabsf(v0.y)); m = fmaxf(m, fabsf(v0.z)); m = fmaxf(m, fabsf(v0.w));
    m = fmaxf(m, fabsf(v1.x)); m = fmaxf(m, fabsf(v1.y)); m = fmaxf(m, fabsf(v1.z)); m = fmaxf(m, fabsf(v1.w));
    m = fmaxf(m, fabsf(v2.x)); m = fmaxf(m, fabsf(v2.y)); m = fmaxf(m, fabsf(v2.z)); m = fmaxf(m, fabsf(v2.w));
    m = fmaxf(m, fabsf(v3.x)); m = fmaxf(m, fabsf(v3.y)); m = fmaxf(m, fabsf(v3.z)); m = fmaxf(m, fabsf(v3.w));
    #pragma unroll
    for (int o = 32; o > 0; o >>= 1) m = fmaxf(m, __shfl_xor(m, o));
    if ((t & 63) == 0) red[t >> 6] = m;
    __syncthreads();
    m = fmaxf(fmaxf(red[0], red[1]), fmaxf(red[2], red[3]));
    m = fmaxf(m, 1e-20f);
    const float inv = 127.0f / m;
    if (t == 0) xs[row] = m / 127.0f;
    union { signed char c[16]; int4 i; } r;
    #pragma unroll
    for (int j = 0; j < 4; ++j) {
        float4 v = (j == 0) ? v0 : (j == 1) ? v1 : (j == 2) ? v2 : v3;
        r.c[j*4+0] = (signed char)(int)rintf(fminf(fmaxf(v.x*inv,-127.f),127.f));
        r.c[j*4+1] = (signed char)(int)rintf(fminf(fmaxf(v.y*inv,-127.f),127.f));
        r.c[j*4+2] = (signed char)(int)rintf(fminf(fmaxf(v.z*inv,-127.f),127.f));
        r.c[j*4+3] = (signed char)(int)rintf(fminf(fmaxf(v.w*inv,-127.f),127.f));
    }
    *(int4*)(xq + (size_t)row * D_MODEL + t * 16) = r.i;
}

// ---------------------------------------------------------------------------
// Fused gate+up i8 GEMM (r7 form). BK=64, 4-ring of 32KB {A 16K, B 16K}.
// Step = 2 phases (8+4 ds_reads, 16 MFMA each) with barrier pairs;
// stage s+2 during s; vmcnt(4) once per step.
// ---------------------------------------------------------------------------
__global__ __launch_bounds__(512, 2)
void gemm_i8gu(const signed char* __restrict__ A,
               const signed char* __restrict__ B,   // interleaved [2*D_FF][K]
               unsigned short* __restrict__ H,
               const float* __restrict__ xs,
               const float* __restrict__ gs,
               const float* __restrict__ us,
               int M, int NH, int K)
{
    extern __shared__ char smem[];
    const int tid = threadIdx.x;
    const int l   = tid & 63;
    const int w   = tid >> 6;
    const int wm  = w >> 2;
    const int wn  = w & 3;

    const int nbx  = gridDim.x;
    const int nwg  = nbx * gridDim.y;
    const int orig = blockIdx.y * nbx + blockIdx.x;
    const int cpx  = nwg >> 3;
    const int swz  = (orig & 7) * cpx + (orig >> 3);
    const int bn = swz % nbx, bm = swz / nbx;
    const int m0 = bm * 256, n0 = bn * 256;

    const int st_r = tid >> 2;
    const int st_c = ((tid & 3) ^ ((st_r >> 1) & 3)) << 4;
    const signed char* gA = A + (size_t)(m0 + st_r) * K + st_c;
    const signed char* gB = B + (size_t)(n0 + st_r) * K + st_c;
    const size_t ld128 = (size_t)128 * K;

    const int s4v = l >> 4;
    const int rA = wm * 128 + (l & 15);
    const int rB = wn * 64  + (l & 15);
    const int offA = rA * 64 + ((s4v << 4) ^ (((rA >> 1) & 3) << 4));
    const int offB = 16384 + rB * 64 + ((s4v << 4) ^ (((rB >> 1) & 3) << 4));

    i32x4 acc[8][4] = {};
    i32x4 af[4], bfr[4];

#define SBAR()  __builtin_amdgcn_sched_barrier(0)
#define BAR()   __builtin_amdgcn_s_barrier()
#define VM4()   asm volatile("s_waitcnt vmcnt(4)" ::: "memory")

#define ST_A8(SS, NXT) do { \
    const signed char* p_ = gA + ((size_t)(SS) << 6); \
    gload_lds16(p_,         smem + (NXT) + (w << 10)); \
    gload_lds16(p_ + ld128, smem + (NXT) + 8192 + (w << 10)); } while (0)
#define ST_B8(SS, NXT) do { \
    const signed char* p_ = gB + ((size_t)(SS) << 6); \
    gload_lds16(p_,         smem + (NXT) + 16384 + (w << 10)); \
    gload_lds16(p_ + ld128, smem + (NXT) + 16384 + 8192 + (w << 10)); } while (0)

#define MFMA16_I8(MB) do { \
    _Pragma("unroll") \
    for (int mi_ = 0; mi_ < 4; ++mi_) { \
        _Pragma("unroll") \
        for (int ni_ = 0; ni_ < 4; ++ni_) { \
            acc[(MB) + mi_][ni_] = __builtin_amdgcn_mfma_i32_16x16x64_i8( \
                af[mi_], bfr[ni_], acc[(MB) + mi_][ni_], 0, 0, 0); \
        } } } while (0)

#define STEP8(CUR, NXT, SS) do { \
    af[0]  = *(const i32x4*)(smem + (CUR) + offA); \
    af[1]  = *(const i32x4*)(smem + (CUR) + offA + 1024); \
    af[2]  = *(const i32x4*)(smem + (CUR) + offA + 2048); \
    af[3]  = *(const i32x4*)(smem + (CUR) + offA + 3072); \
    bfr[0] = *(const i32x4*)(smem + (CUR) + offB); \
    bfr[1] = *(const i32x4*)(smem + (CUR) + offB + 1024); \
    bfr[2] = *(const i32x4*)(smem + (CUR) + offB + 2048); \
    bfr[3] = *(const i32x4*)(smem + (CUR) + offB + 3072); \
    ST_A8(SS, NXT); \
    SBAR(); BAR(); \
    __builtin_amdgcn_s_setprio(1); MFMA16_I8(0); __builtin_amdgcn_s_setprio(0); \
    SBAR(); BAR(); \
    af[0] = *(const i32x4*)(smem + (CUR) + offA + 4096); \
    af[1] = *(const i32x4*)(smem + (CUR) + offA + 5120); \
    af[2] = *(const i32x4*)(smem + (CUR) + offA + 6144); \
    af[3] = *(const i32x4*)(smem + (CUR) + offA + 7168); \
    ST_B8(SS, NXT); \
    SBAR(); BAR(); \
    __builtin_amdgcn_s_setprio(1); MFMA16_I8(4); __builtin_amdgcn_s_setprio(0); \
    VM4(); SBAR(); BAR(); \
} while (0)

    ST_A8(0, 0);      ST_B8(0, 0);
    ST_A8(1, 32768);  ST_B8(1, 32768);
    VM4(); SBAR(); BAR();

    const int T = K >> 6;            // 64; T%4==0
    #pragma unroll 1
    for (int s = 0; s < T; s += 4) {
        int s2 = s + 2; if (s2 >= T) s2 -= T;
        int s3 = s + 3; if (s3 >= T) s3 -= T;
        int s4 = s + 4; if (s4 >= T) s4 -= T;
        int s5 = s + 5; if (s5 >= T) s5 -= T;
        STEP8(0,     65536, s2);
        STEP8(32768, 98304, s3);
        STEP8(65536, 0,     s4);
        STEP8(98304, 32768, s5);
    }
    asm volatile("s_waitcnt vmcnt(0)" ::: "memory");

    // epilogue: ni even = gate, ni odd = up (16-row interleave)
    const int er = (l >> 4) * 4;
    const int ec = l & 15;
    const int hbase = (n0 >> 1) + wn * 32;
    #pragma unroll
    for (int mi = 0; mi < 8; ++mi) {
        const int rowb = m0 + wm * 128 + mi * 16 + er;
        const float4 xsv = *(const float4*)(xs + rowb);
        #pragma unroll
        for (int p = 0; p < 2; ++p) {
            const int c = hbase + p * 16 + ec;
            const float sg = gs[c];
            const float su = us[c];
            #pragma unroll
            for (int q = 0; q < 4; ++q) {
                const float xsc = (q == 0) ? xsv.x : (q == 1) ? xsv.y
                                 : (q == 2) ? xsv.z : xsv.w;
                float g = (float)acc[mi][2*p][q]     * sg * xsc;
                float u = (float)acc[mi][2*p + 1][q] * su * xsc;
                float sig = 1.0f / (1.0f + __expf(-g));
                H[(size_t)(rowb + q) * NH + c] = f32_to_bf16(g * sig * u);
            }
        }
    }
#undef STEP8
#undef MFMA16_I8
#undef ST_A8
#undef ST_B8
#undef VM4
#undef BAR
#undef SBAR
}

// ---------------------------------------------------------------------------
// Down-proj bf16 GEMM (r10 form). BK=32 steps, 4-ring of 32KB {A 16K, B 16K}.
// One barrier region per step (12 ds_reads + 32 MFMA), vmcnt(4)/step. T=344.
// ---------------------------------------------------------------------------
__global__ __launch_bounds__(512, 2)
void gemm256_down(const unsigned short* __restrict__ A,
                  const unsigned short* __restrict__ B,
                  float* __restrict__ C,
                  int M, int N, int K)
{
    extern __shared__ char smem[];
    const int tid = threadIdx.x;
    const int l   = tid & 63;
    const int w   = tid >> 6;
    const int wm  = w >> 2;
    const int wn  = w & 3;

    const int nbx  = gridDim.x;
    const int nwg  = nbx * gridDim.y;
    const int orig = blockIdx.y * nbx + blockIdx.x;
    const int cpx  = nwg >> 3;
    const int swz  = (orig & 7) * cpx + (orig >> 3);
    const int bn = swz % nbx, bm = swz / nbx;
    const int m0 = bm * 256, n0 = bn * 256;

    const int st_r = tid >> 2;
    const int st_c = ((tid & 3) ^ ((st_r >> 1) & 3)) << 3;   // elems (bf16)
    const unsigned short* gA = A + (size_t)(m0 + st_r) * K + st_c;
    const unsigned short* gB = B + (size_t)(n0 + st_r) * K + st_c;
    const size_t ld128 = (size_t)128 * K;

    const int s4v = l >> 4;
    const int rA = wm * 128 + (l & 15);
    const int rB = wn * 64  + (l & 15);
    const int offA = rA * 64 + ((s4v << 4) ^ (((rA >> 1) & 3) << 4));
    const int offB = 16384 + rB * 64 + ((s4v << 4) ^ (((rB >> 1) & 3) << 4));

    f32x4 acc[8][4] = {};
    bf16x8 af[8], bfr[4];

#define SBAR()  __builtin_amdgcn_sched_barrier(0)
#define BAR()   __builtin_amdgcn_s_barrier()
#define VM4()   asm volatile("s_waitcnt vmcnt(4)" ::: "memory")

#define ST_A2(SS, NXT) do { \
    const unsigned short* p_ = gA + ((size_t)(SS) << 5); \
    gload_lds16(p_,         smem + (NXT) + (w << 10)); \
    gload_lds16(p_ + ld128, smem + (NXT) + 8192 + (w << 10)); } while (0)
#define ST_B2(SS, NXT) do { \
    const unsigned short* p_ = gB + ((size_t)(SS) << 5); \
    gload_lds16(p_,         smem + (NXT) + 16384 + (w << 10)); \
    gload_lds16(p_ + ld128, smem + (NXT) + 16384 + 8192 + (w << 10)); } while (0)

#define STEPD(CUR, NXT, SS) do { \
    ST_A2(SS, NXT); \
    ST_B2(SS, NXT); \
    af[0] = *(const bf16x8*)(smem + (CUR) + offA); \
    af[1] = *(const bf16x8*)(smem + (CUR) + offA + 1024); \
    af[2] = *(const bf16x8*)(smem + (CUR) + offA + 2048); \
    af[3] = *(const bf16x8*)(smem + (CUR) + offA + 3072); \
    af[4] = *(const bf16x8*)(smem + (CUR) + offA + 4096); \
    af[5] = *(const bf16x8*)(smem + (CUR) + offA + 5120); \
    af[6] = *(const bf16x8*)(smem + (CUR) + offA + 6144); \
    af[7] = *(const bf16x8*)(smem + (CUR) + offA + 7168); \
    bfr[0] = *(const bf16x8*)(smem + (CUR) + offB); \
    bfr[1] = *(const bf16x8*)(smem + (CUR) + offB + 1024); \
    bfr[2] = *(const bf16x8*)(smem + (CUR) + offB + 2048); \
    bfr[3] = *(const bf16x8*)(smem + (CUR) + offB + 3072); \
    __builtin_amdgcn_s_setprio(1); \
    _Pragma("unroll") \
    for (int mi_ = 0; mi_ < 8; ++mi_) { \
        _Pragma("unroll") \
        for (int ni_ = 0; ni_ < 4; ++ni_) { \
            acc[mi_][ni_] = __builtin_amdgcn_mfma_f32_16x16x32_bf16( \
                af[mi_], bfr[ni_], acc[mi_][ni_], 0, 0, 0); \
        } } \
    __builtin_amdgcn_s_setprio(0); \
    VM4(); SBAR(); BAR(); \
} while (0)

    ST_A2(0, 0);      ST_B2(0, 0);
    ST_A2(1, 32768);  ST_B2(1, 32768);
    VM4(); SBAR(); BAR();

    const int T = K >> 5;            // 344; T%4==0
    #pragma unroll 1
    for (int s = 0; s < T; s += 4) {
        int s2 = s + 2; if (s2 >= T) s2 -= T;
        int s3 = s + 3; if (s3 >= T) s3 -= T;
        int s4 = s + 4; if (s4 >= T) s4 -= T;
        int s5 = s + 5; if (s5 >= T) s5 -= T;
        STEPD(0,     65536, s2);
        STEPD(32768, 98304, s3);
        STEPD(65536, 0,     s4);
        STEPD(98304, 32768, s5);
    }
    asm volatile("s_waitcnt vmcnt(0)" ::: "memory");

    const int er = (l >> 4) * 4;
    const int ec = l & 15;
    #pragma unroll
    for (int mi = 0; mi < 8; ++mi) {
        #pragma unroll
        for (int ni = 0; ni < 4; ++ni) {
            #pragma unroll
            for (int q = 0; q < 4; ++q) {
                int row = m0 + wm * 128 + mi * 16 + er + q;
                int col = n0 + wn * 64  + ni * 16 + ec;
                C[(size_t)row * N + col] = acc[mi][ni][q];
            }
        }
    }
#undef STEPD
#undef ST_A2
#undef ST_B2
#undef VM4
#undef BAR
#undef SBAR
}

extern "C" void kernel_launch(void* const* d_in, const int* in_sizes, int n_in,
                              void* d_out, int out_size, void* d_ws, size_t ws_size,
                              hipStream_t stream)
{
    const float* x  = (const float*)d_in[0];
    const int*   gw = (const int*)  d_in[1];
    const float* gs = (const float*)d_in[2];
    const int*   uw = (const int*)  d_in[3];
    const float* us = (const float*)d_in[4];
    const int*   dw = (const int*)  d_in[5];
    const float* dsc= (const float*)d_in[6];

    char* ws = (char*)d_ws;
    signed char*    Xq   = (signed char*)ws;    ws += (size_t)NTOK * D_MODEL;
    float*          xs   = (float*)ws;          ws += (size_t)NTOK * 4;
    signed char*    Wgu8 = (signed char*)ws;    ws += (size_t)2 * D_FF * D_MODEL;
    unsigned short* Wd   = (unsigned short*)ws; ws += (size_t)D_MODEL * D_FF * 2;
    unsigned short* H    = (unsigned short*)ws;

    const long long wtot  = (long long)D_FF * D_MODEL;
    const long long gutot = 2LL * wtot;

    hipFuncSetAttribute(reinterpret_cast<const void*>(gemm_i8gu),
                        hipFuncAttributeMaxDynamicSharedMemorySize, 131072);
    hipFuncSetAttribute(reinterpret_cast<const void*>(gemm256_down),
                        hipFuncAttributeMaxDynamicSharedMemorySize, 131072);

    pack_gu_kernel  <<<(int)(gutot / 2048), 256, 0, stream>>>(gw, uw, Wgu8);
    dequant_w_kernel<<<(int)(wtot  / 2048), 256, 0, stream>>>(dw, dsc, Wd, D_FF, wtot);
    quant_x_kernel  <<<NTOK, 256, 0, stream>>>(x, Xq, xs);

    // fused gate+up: H = silu(Xq@Wg^T * gs*xs) * (Xq@Wu^T * us*xs)
    dim3 g1(2 * D_FF / 256, NTOK / 256);   // 86 x 32 = 2752 blocks (%8==0)
    gemm_i8gu<<<g1, 512, 131072, stream>>>(Xq, Wgu8, H, xs, gs, us,
                                           NTOK, D_FF, D_MODEL);

    // out = H @ Wd^T -> f32
    dim3 g3(D_MODEL / 256, NTOK / 256);    // 16 x 32 = 512 blocks (%8==0)
    gemm256_down<<<g3, 512, 131072, stream>>>(H, Wd, (float*)d_out,
                                              NTOK, D_MODEL, D_FF);
}

// Round 15
// 1543.061 us; speedup vs baseline: 1.1213x; 1.0171x over previous
//
#include <hip/hip_runtime.h>

// ---------------------------------------------------------------------------
// SharedOnlyMLP FINAL (= r7, best measured: 1538.8 us, absmax 2816/4178):
//   prepass: pack_gu (Wg/Wu -> interleaved int8, 16-row groups),
//            dequant_w (Wd -> bf16, scale folded), quant_x (x -> per-row i8).
//   gemm_i8gu: ONE i8 GEMM computes gate+up (interleaved B); 256x256 tile,
//     BK=64, mfma_i32_16x16x64_i8, 4-ring 32KB LDS slots, XOR swizzle both
//     sides, 2 phases/step with barrier pairs, counted vmcnt(4)/step,
//     in-register h = silu(g*sg*xs)*(u*su*xs) epilogue (no gate round-trip).
//   gemm256_down: bf16 256x256, BK=64 2-buffer 4-phase (r2-proven), f32 out.
//   Session invariant: step ~= LDS-time + MFMA-time; all plain-HIP desync
//   levers (deep ring / merged barriers / reg prefetch / 2 blocks/CU /
//   fat waves / 32x32 shapes / B-direct) are neutral or regress.
// ---------------------------------------------------------------------------

typedef __attribute__((ext_vector_type(8))) __bf16 bf16x8;
typedef __attribute__((ext_vector_type(4))) float f32x4;
typedef __attribute__((ext_vector_type(8))) unsigned short ushort8;
typedef __attribute__((ext_vector_type(4))) int i32x4;

#define D_MODEL 4096
#define D_FF    11008
#define NTOK    8192

static __device__ __forceinline__ unsigned short f32_to_bf16(float f) {
    union { float f; unsigned u; } v; v.f = f;
    unsigned r = v.u + 0x7fffu + ((v.u >> 16) & 1u);
    return (unsigned short)(r >> 16);
}
static __device__ __forceinline__ float bf16_to_f32(unsigned short s) {
    union { unsigned u; float f; } v; v.u = ((unsigned)s) << 16;
    return v.f;
}
static __device__ __forceinline__ void gload_lds16(const void* g, void* l) {
    __builtin_amdgcn_global_load_lds(
        (const __attribute__((address_space(1))) void*)g,
        (__attribute__((address_space(3))) void*)l, 16, 0, 0);
}

// ---- pack gate+up int32 -> interleaved int8 (16-row groups) ----
// out row r (0..2*D_FF): type=(r>>4)&1 (0=gate,1=up), src_row=((r>>5)<<4)+(r&15)
__global__ __launch_bounds__(256)
void pack_gu_kernel(const int* __restrict__ gw, const int* __restrict__ uw,
                    signed char* __restrict__ out)
{
    long long i = ((long long)blockIdx.x * 256 + threadIdx.x) * 8;
    const int r = (int)(i >> 12);           // / D_MODEL (4096)
    const int k = (int)(i & 4095);
    const int src_row = ((r >> 5) << 4) + (r & 15);
    const int* src = ((r >> 4) & 1) ? uw : gw;
    const int* p = src + (size_t)src_row * D_MODEL + k;
    int4 w0 = *(const int4*)(p);
    int4 w1 = *(const int4*)(p + 4);
    union { signed char c[8]; unsigned long long u; } rr;
    rr.c[0] = (signed char)w0.x; rr.c[1] = (signed char)w0.y;
    rr.c[2] = (signed char)w0.z; rr.c[3] = (signed char)w0.w;
    rr.c[4] = (signed char)w1.x; rr.c[5] = (signed char)w1.y;
    rr.c[6] = (signed char)w1.z; rr.c[7] = (signed char)w1.w;
    *(unsigned long long*)(out + i) = rr.u;
}

// ---- weight dequant (down-proj): int32 * s[row] -> bf16 ----
__global__ __launch_bounds__(256)
void dequant_w_kernel(const int* __restrict__ w, const float* __restrict__ s,
                      unsigned short* __restrict__ out, int cols, long long total)
{
    long long i = ((long long)blockIdx.x * 256 + threadIdx.x) * 8;
    if (i >= total) return;
    float sc = s[(int)(i / cols)];
    int4 w0 = *(const int4*)(w + i);
    int4 w1 = *(const int4*)(w + i + 4);
    ushort8 r;
    r[0] = f32_to_bf16((float)w0.x * sc);
    r[1] = f32_to_bf16((float)w0.y * sc);
    r[2] = f32_to_bf16((float)w0.z * sc);
    r[3] = f32_to_bf16((float)w0.w * sc);
    r[4] = f32_to_bf16((float)w1.x * sc);
    r[5] = f32_to_bf16((float)w1.y * sc);
    r[6] = f32_to_bf16((float)w1.z * sc);
    r[7] = f32_to_bf16((float)w1.w * sc);
    *(ushort8*)(out + i) = r;
}

// ---- x: f32 -> per-row int8 + scale ----
__global__ __launch_bounds__(256)
void quant_x_kernel(const float* __restrict__ x, signed char* __restrict__ xq,
                    float* __restrict__ xs)
{
    __shared__ float red[4];
    const int row = blockIdx.x;
    const int t   = threadIdx.x;
    const float* xr = x + (size_t)row * D_MODEL;
    float4 v0 = *(const float4*)(xr + t * 16);
    float4 v1 = *(const float4*)(xr + t * 16 + 4);
    float4 v2 = *(const float4*)(xr + t * 16 + 8);
    float4 v3 = *(const float4*)(xr + t * 16 + 12);
    float m = fabsf(v0.x);
    m = fmaxf(m, fabsf(v0.y)); m = fmaxf(m, fabsf(v0.z)); m = fmaxf(m, fabsf(v0.w));
    m = fmaxf(m, fabsf(v1.x)); m = fmaxf(m, fabsf(v1.y)); m = fmaxf(m, fabsf(v1.z)); m = fmaxf(m, fabsf(v1.w));
    m = fmaxf(m, fabsf(v2.x)); m = fmaxf(m, fabsf(v2.y)); m = fmaxf(m, fabsf(v2.z)); m = fmaxf(m, fabsf(v2.w));
    m = fmaxf(m, fabsf(v3.x)); m = fmaxf(m, fabsf(v3.y)); m = fmaxf(m, fabsf(v3.z)); m = fmaxf(m, fabsf(v3.w));
    #pragma unroll
    for (int o = 32; o > 0; o >>= 1) m = fmaxf(m, __shfl_xor(m, o));
    if ((t & 63) == 0) red[t >> 6] = m;
    __syncthreads();
    m = fmaxf(fmaxf(red[0], red[1]), fmaxf(red[2], red[3]));
    m = fmaxf(m, 1e-20f);
    const float inv = 127.0f / m;
    if (t == 0) xs[row] = m / 127.0f;
    union { signed char c[16]; int4 i; } r;
    #pragma unroll
    for (int j = 0; j < 4; ++j) {
        float4 v = (j == 0) ? v0 : (j == 1) ? v1 : (j == 2) ? v2 : v3;
        r.c[j*4+0] = (signed char)(int)rintf(fminf(fmaxf(v.x*inv,-127.f),127.f));
        r.c[j*4+1] = (signed char)(int)rintf(fminf(fmaxf(v.y*inv,-127.f),127.f));
        r.c[j*4+2] = (signed char)(int)rintf(fminf(fmaxf(v.z*inv,-127.f),127.f));
        r.c[j*4+3] = (signed char)(int)rintf(fminf(fmaxf(v.w*inv,-127.f),127.f));
    }
    *(int4*)(xq + (size_t)row * D_MODEL + t * 16) = r.i;
}

// ---------------------------------------------------------------------------
// Fused gate+up i8 GEMM over interleaved B (2*D_FF rows):
//   h[row][c] = silu(acc_gate * gs[c] * xs[row]) * (acc_up * us[c] * xs[row])
// 256x256 interleaved tile = 128 h-cols.
// ---------------------------------------------------------------------------
__global__ __launch_bounds__(512, 2)
void gemm_i8gu(const signed char* __restrict__ A,
               const signed char* __restrict__ B,   // interleaved [2*D_FF][K]
               unsigned short* __restrict__ H,      // [M][NH]
               const float* __restrict__ xs,
               const float* __restrict__ gs,
               const float* __restrict__ us,
               int M, int NH, int K)
{
    extern __shared__ char smem[];
    const int tid = threadIdx.x;
    const int l   = tid & 63;
    const int w   = tid >> 6;
    const int wm  = w >> 2;
    const int wn  = w & 3;

    const int nbx  = gridDim.x;
    const int nwg  = nbx * gridDim.y;
    const int orig = blockIdx.y * nbx + blockIdx.x;
    const int cpx  = nwg >> 3;
    const int swz  = (orig & 7) * cpx + (orig >> 3);
    const int bn = swz % nbx, bm = swz / nbx;
    const int m0 = bm * 256, n0 = bn * 256;     // n0 over interleaved rows

    // staging: thread t -> row t>>2, 16-B chunk (t&3), source pre-swizzled
    const int st_r = tid >> 2;
    const int st_c = ((tid & 3) ^ ((st_r >> 1) & 3)) << 4;
    const signed char* gA = A + (size_t)(m0 + st_r) * K + st_c;
    const signed char* gB = B + (size_t)(n0 + st_r) * K + st_c;
    const size_t ld128 = (size_t)128 * K;

    // ds_read offsets (swizzled), row stride 64 B
    const int s4v = l >> 4;
    const int rA = wm * 128 + (l & 15);
    const int rB = wn * 64  + (l & 15);
    const int offA = rA * 64 + ((s4v << 4) ^ (((rA >> 1) & 3) << 4));
    const int offB = 16384 + rB * 64 + ((s4v << 4) ^ (((rB >> 1) & 3) << 4));

    i32x4 acc[8][4] = {};
    i32x4 af[4], bfr[4];

#define SBAR()  __builtin_amdgcn_sched_barrier(0)
#define BAR()   __builtin_amdgcn_s_barrier()
#define VM4()   asm volatile("s_waitcnt vmcnt(4)" ::: "memory")

#define ST_A8(SS, NXT) do { \
    const signed char* p_ = gA + ((size_t)(SS) << 6); \
    gload_lds16(p_,         smem + (NXT) + (w << 10)); \
    gload_lds16(p_ + ld128, smem + (NXT) + 8192 + (w << 10)); } while (0)
#define ST_B8(SS, NXT) do { \
    const signed char* p_ = gB + ((size_t)(SS) << 6); \
    gload_lds16(p_,         smem + (NXT) + 16384 + (w << 10)); \
    gload_lds16(p_ + ld128, smem + (NXT) + 16384 + 8192 + (w << 10)); } while (0)

#define MFMA16_I8(MB) do { \
    _Pragma("unroll") \
    for (int mi_ = 0; mi_ < 4; ++mi_) { \
        _Pragma("unroll") \
        for (int ni_ = 0; ni_ < 4; ++ni_) { \
            acc[(MB) + mi_][ni_] = __builtin_amdgcn_mfma_i32_16x16x64_i8( \
                af[mi_], bfr[ni_], acc[(MB) + mi_][ni_], 0, 0, 0); \
        } } } while (0)

#define STEP8(CUR, NXT, SS) do { \
    af[0]  = *(const i32x4*)(smem + (CUR) + offA); \
    af[1]  = *(const i32x4*)(smem + (CUR) + offA + 1024); \
    af[2]  = *(const i32x4*)(smem + (CUR) + offA + 2048); \
    af[3]  = *(const i32x4*)(smem + (CUR) + offA + 3072); \
    bfr[0] = *(const i32x4*)(smem + (CUR) + offB); \
    bfr[1] = *(const i32x4*)(smem + (CUR) + offB + 1024); \
    bfr[2] = *(const i32x4*)(smem + (CUR) + offB + 2048); \
    bfr[3] = *(const i32x4*)(smem + (CUR) + offB + 3072); \
    ST_A8(SS, NXT); \
    SBAR(); BAR(); \
    __builtin_amdgcn_s_setprio(1); MFMA16_I8(0); __builtin_amdgcn_s_setprio(0); \
    SBAR(); BAR(); \
    af[0] = *(const i32x4*)(smem + (CUR) + offA + 4096); \
    af[1] = *(const i32x4*)(smem + (CUR) + offA + 5120); \
    af[2] = *(const i32x4*)(smem + (CUR) + offA + 6144); \
    af[3] = *(const i32x4*)(smem + (CUR) + offA + 7168); \
    ST_B8(SS, NXT); \
    SBAR(); BAR(); \
    __builtin_amdgcn_s_setprio(1); MFMA16_I8(4); __builtin_amdgcn_s_setprio(0); \
    VM4(); SBAR(); BAR(); \
} while (0)

    ST_A8(0, 0);      ST_B8(0, 0);
    ST_A8(1, 32768);  ST_B8(1, 32768);
    VM4(); SBAR(); BAR();

    const int T = K >> 6;            // 64; T%4==0
    #pragma unroll 1
    for (int s = 0; s < T; s += 4) {
        int s2 = s + 2; if (s2 >= T) s2 -= T;
        int s3 = s + 3; if (s3 >= T) s3 -= T;
        int s4 = s + 4; if (s4 >= T) s4 -= T;
        int s5 = s + 5; if (s5 >= T) s5 -= T;
        STEP8(0,     65536, s2);
        STEP8(32768, 98304, s3);
        STEP8(65536, 0,     s4);
        STEP8(98304, 32768, s5);
    }
    asm volatile("s_waitcnt vmcnt(0)" ::: "memory");

    // epilogue: interleaved ni pairs -> h = silu(g)*u
    const int er = (l >> 4) * 4;
    const int ec = l & 15;
    const int hbase = (n0 >> 1) + wn * 32;
    #pragma unroll
    for (int mi = 0; mi < 8; ++mi) {
        const int rowb = m0 + wm * 128 + mi * 16 + er;
        const float4 xsv = *(const float4*)(xs + rowb);
        #pragma unroll
        for (int p = 0; p < 2; ++p) {
            const int c = hbase + p * 16 + ec;
            const float sg = gs[c];
            const float su = us[c];
            #pragma unroll
            for (int q = 0; q < 4; ++q) {
                const float xsc = (q == 0) ? xsv.x : (q == 1) ? xsv.y
                                 : (q == 2) ? xsv.z : xsv.w;
                float g = (float)acc[mi][2*p][q]     * sg * xsc;
                float u = (float)acc[mi][2*p + 1][q] * su * xsc;
                float sig = 1.0f / (1.0f + __expf(-g));
                H[(size_t)(rowb + q) * NH + c] = f32_to_bf16(g * sig * u);
            }
        }
    }
#undef STEP8
#undef MFMA16_I8
#undef ST_A8
#undef ST_B8
#undef VM4
#undef BAR
#undef SBAR
}

// ---------------------------------------------------------------------------
// Down-proj bf16 GEMM — r2/r6-proven structure (BK=64 2-buffer, 4 phases).
// ---------------------------------------------------------------------------
__global__ __launch_bounds__(512, 2)
void gemm256_down(const unsigned short* __restrict__ A,
                  const unsigned short* __restrict__ B,
                  float* __restrict__ C,
                  int M, int N, int K)
{
    extern __shared__ char smem[];
    const int tid = threadIdx.x;
    const int l   = tid & 63;
    const int w   = tid >> 6;
    const int wm  = w >> 2;
    const int wn  = w & 3;

    const int nbx  = gridDim.x;
    const int nwg  = nbx * gridDim.y;
    const int orig = blockIdx.y * nbx + blockIdx.x;
    const int cpx  = nwg >> 3;
    const int swz  = (orig & 7) * cpx + (orig >> 3);
    const int bn = swz % nbx, bm = swz / nbx;
    const int m0 = bm * 256, n0 = bn * 256;

    const int st_r = w * 16 + (l >> 2);
    const int st_c = (((l & 3) ^ ((l >> 3) & 3)) << 3);
    const unsigned short* gA = A + (size_t)(m0 + st_r) * K + st_c;
    const unsigned short* gB = B + (size_t)(n0 + st_r) * K + st_c;
    const size_t ld128 = (size_t)128 * K;

    const int s4v = l >> 4;
    const int rA = wm * 128 + (l & 15);
    const int rB = wn * 64  + (l & 15);
    const int offA = rA * 64 + ((s4v << 4) ^ (((rA >> 1) & 3) << 4));
    const int offB = 32768 + rB * 64 + ((s4v << 4) ^ (((rB >> 1) & 3) << 4));

    f32x4 acc[8][4] = {};
    bf16x8 af[4], bfr[4];

#define SBAR()  __builtin_amdgcn_sched_barrier(0)
#define BAR()   __builtin_amdgcn_s_barrier()
#define VM4()   asm volatile("s_waitcnt vmcnt(4)" ::: "memory")
#define STAGE2(SRC, LOFF) do { \
    gload_lds16((SRC), smem + (LOFF) + (w << 10)); \
    gload_lds16((SRC) + ld128, smem + (LOFF) + 8192 + (w << 10)); } while (0)

#define MFMA16(MB) do { \
    _Pragma("unroll") \
    for (int mi_ = 0; mi_ < 4; ++mi_) { \
        _Pragma("unroll") \
        for (int ni_ = 0; ni_ < 4; ++ni_) { \
            acc[(MB) + mi_][ni_] = __builtin_amdgcn_mfma_f32_16x16x32_bf16( \
                af[mi_], bfr[ni_], acc[(MB) + mi_][ni_], 0, 0, 0); \
        } } } while (0)

#define TILE(DB, KTN) do { \
    const int CB = (DB) * 65536; \
    const int PB = ((DB) ^ 1) * 65536; \
    const unsigned short* sA = gA + ((size_t)(KTN) << 6); \
    const unsigned short* sB = gB + ((size_t)(KTN) << 6); \
    af[0]  = *(const bf16x8*)(smem + CB + offA); \
    af[1]  = *(const bf16x8*)(smem + CB + offA + 1024); \
    af[2]  = *(const bf16x8*)(smem + CB + offA + 2048); \
    af[3]  = *(const bf16x8*)(smem + CB + offA + 3072); \
    bfr[0] = *(const bf16x8*)(smem + CB + offB); \
    bfr[1] = *(const bf16x8*)(smem + CB + offB + 1024); \
    bfr[2] = *(const bf16x8*)(smem + CB + offB + 2048); \
    bfr[3] = *(const bf16x8*)(smem + CB + offB + 3072); \
    STAGE2(sA, PB); \
    SBAR(); BAR(); \
    __builtin_amdgcn_s_setprio(1); MFMA16(0); __builtin_amdgcn_s_setprio(0); \
    SBAR(); BAR(); \
    af[0] = *(const bf16x8*)(smem + CB + offA + 4096); \
    af[1] = *(const bf16x8*)(smem + CB + offA + 5120); \
    af[2] = *(const bf16x8*)(smem + CB + offA + 6144); \
    af[3] = *(const bf16x8*)(smem + CB + offA + 7168); \
    STAGE2(sB, PB + 32768); \
    SBAR(); BAR(); \
    __builtin_amdgcn_s_setprio(1); MFMA16(4); __builtin_amdgcn_s_setprio(0); \
    VM4(); SBAR(); BAR(); \
    af[0]  = *(const bf16x8*)(smem + CB + 16384 + offA); \
    af[1]  = *(const bf16x8*)(smem + CB + 16384 + offA + 1024); \
    af[2]  = *(const bf16x8*)(smem + CB + 16384 + offA + 2048); \
    af[3]  = *(const bf16x8*)(smem + CB + 16384 + offA + 3072); \
    bfr[0] = *(const bf16x8*)(smem + CB + 16384 + offB); \
    bfr[1] = *(const bf16x8*)(smem + CB + 16384 + offB + 1024); \
    bfr[2] = *(const bf16x8*)(smem + CB + 16384 + offB + 2048); \
    bfr[3] = *(const bf16x8*)(smem + CB + 16384 + offB + 3072); \
    STAGE2(sA + 32, PB + 16384); \
    SBAR(); BAR(); \
    __builtin_amdgcn_s_setprio(1); MFMA16(0); __builtin_amdgcn_s_setprio(0); \
    SBAR(); BAR(); \
    af[0] = *(const bf16x8*)(smem + CB + 16384 + offA + 4096); \
    af[1] = *(const bf16x8*)(smem + CB + 16384 + offA + 5120); \
    af[2] = *(const bf16x8*)(smem + CB + 16384 + offA + 6144); \
    af[3] = *(const bf16x8*)(smem + CB + 16384 + offA + 7168); \
    STAGE2(sB + 32, PB + 49152); \
    SBAR(); BAR(); \
    __builtin_amdgcn_s_setprio(1); MFMA16(4); __builtin_amdgcn_s_setprio(0); \
    VM4(); SBAR(); BAR(); \
} while (0)

    STAGE2(gA,      0);
    STAGE2(gB,      32768);
    STAGE2(gA + 32, 16384);
    STAGE2(gB + 32, 49152);
    VM4(); SBAR(); BAR();

    const int T = K >> 6;
    const int T2 = T >> 1;
    #pragma unroll 1
    for (int it = 0; it < T2; ++it) {
        const int t0 = it << 1;
        TILE(0, t0 + 1);
        const int kt2 = (t0 + 2 == T) ? 0 : (t0 + 2);
        TILE(1, kt2);
    }
    asm volatile("s_waitcnt vmcnt(0)" ::: "memory");

    const int er = (l >> 4) * 4;
    const int ec = l & 15;
    #pragma unroll
    for (int mi = 0; mi < 8; ++mi) {
        #pragma unroll
        for (int ni = 0; ni < 4; ++ni) {
            #pragma unroll
            for (int q = 0; q < 4; ++q) {
                int row = m0 + wm * 128 + mi * 16 + er + q;
                int col = n0 + wn * 64  + ni * 16 + ec;
                C[(size_t)row * N + col] = acc[mi][ni][q];
            }
        }
    }
#undef TILE
#undef MFMA16
#undef STAGE2
#undef VM4
#undef BAR
#undef SBAR
}

extern "C" void kernel_launch(void* const* d_in, const int* in_sizes, int n_in,
                              void* d_out, int out_size, void* d_ws, size_t ws_size,
                              hipStream_t stream)
{
    const float* x  = (const float*)d_in[0];
    const int*   gw = (const int*)  d_in[1];
    const float* gs = (const float*)d_in[2];
    const int*   uw = (const int*)  d_in[3];
    const float* us = (const float*)d_in[4];
    const int*   dw = (const int*)  d_in[5];
    const float* dsc= (const float*)d_in[6];

    // workspace layout (~394 MB)
    char* ws = (char*)d_ws;
    signed char*    Xq   = (signed char*)ws;    ws += (size_t)NTOK * D_MODEL;
    float*          xs   = (float*)ws;          ws += (size_t)NTOK * 4;
    signed char*    Wgu8 = (signed char*)ws;    ws += (size_t)2 * D_FF * D_MODEL;
    unsigned short* Wd   = (unsigned short*)ws; ws += (size_t)D_MODEL * D_FF * 2;
    unsigned short* H    = (unsigned short*)ws;

    const long long wtot  = (long long)D_FF * D_MODEL;
    const long long gutot = 2LL * wtot;

    hipFuncSetAttribute(reinterpret_cast<const void*>(gemm_i8gu),
                        hipFuncAttributeMaxDynamicSharedMemorySize, 131072);
    hipFuncSetAttribute(reinterpret_cast<const void*>(gemm256_down),
                        hipFuncAttributeMaxDynamicSharedMemorySize, 131072);

    pack_gu_kernel  <<<(int)(gutot / 2048), 256, 0, stream>>>(gw, uw, Wgu8);
    dequant_w_kernel<<<(int)(wtot  / 2048), 256, 0, stream>>>(dw, dsc, Wd, D_FF, wtot);
    quant_x_kernel  <<<NTOK, 256, 0, stream>>>(x, Xq, xs);

    // fused gate+up: H = silu(Xq@Wg^T * gs*xs) * (Xq@Wu^T * us*xs)
    dim3 g1(2 * D_FF / 256, NTOK / 256);   // 86 x 32 = 2752 blocks (%8==0)
    gemm_i8gu<<<g1, 512, 131072, stream>>>(Xq, Wgu8, H, xs, gs, us,
                                           NTOK, D_FF, D_MODEL);

    // out = H @ Wd^T -> f32
    dim3 g3(D_MODEL / 256, NTOK / 256);    // 16 x 32 = 512 blocks (%8==0)
    gemm256_down<<<g3, 512, 131072, stream>>>(H, Wd, (float*)d_out,
                                              NTOK, D_MODEL, D_FF);
}